// Round 22
// baseline (446.382 us; speedup 1.0000x reference)
//
#include <hip/hip_runtime.h>
#include <math.h>

constexpr int Hc = 80, Wc = 80, Bn = 4, C1 = 256, C2 = 256;
constexpr int HWn = Hc * Wc;          // 6400
constexpr int NPIX = Bn * HWn;        // 25600
constexpr int OFFC = 27;
constexpr int KK   = 2304;            // C1*9

typedef short bf16x8 __attribute__((ext_vector_type(8)));
typedef float f32x4  __attribute__((ext_vector_type(4)));

__device__ __forceinline__ unsigned f2bf(float f) {   // RNE to bf16 bits
    unsigned u = __float_as_uint(f);
    return (u + 0x7FFF + ((u >> 16) & 1)) >> 16;
}

// pack 2 floats -> 1 u32 of 2 bf16 via cvt_pk (RNE)
__device__ __forceinline__ unsigned packhi2(float v0, float v1) {
    unsigned h;
    asm("v_cvt_pk_bf16_f32 %0, %1, %2" : "=v"(h) : "v"(v0), "v"(v1));
    return h;
}

// ---------------- kernel 0a: weight prep -> per-step B images, K-MAJOR ----------
// wB1[s][kg][oc][8] bf16, s = p*8+cc (72 steps), kg = k-quad (8 k each).
__global__ __launch_bounds__(256) void k_wprep(const float* __restrict__ weight,
                                               unsigned short* __restrict__ wB1)
{
    int e = blockIdx.x * 256 + threadIdx.x;   // 0 .. 589823
    int kin = e & 7;
    int oc  = (e >> 3) & 255;
    int kg  = (e >> 11) & 3;
    int s   = e >> 13;                        // 0..71
    int p   = s >> 3, cc = s & 7;
    float w = weight[((size_t)oc * C1 + cc * 32 + kg * 8 + kin) * 9 + p];
    wB1[e] = (unsigned short)f2bf(w);
}

// ---------------- kernel 0b: offset-conv MFMA weight prep -> wOB[s][32][32] ----
__global__ __launch_bounds__(256) void k_wobprep(const float* __restrict__ w_off,
                                                 unsigned short* __restrict__ wOB)
{
    int e = blockIdx.x * 256 + threadIdx.x;   // 0 .. 73727
    int k  = e & 31;
    int oc = (e >> 5) & 31;
    int s  = e >> 10;                         // 0..71
    int p  = s >> 3, cc = s & 7;
    float v = 0.f;
    if (oc < 27) v = w_off[((size_t)oc * C1 + cc * 32 + k) * 9 + p];
    wOB[e] = (unsigned short)f2bf(v);
}

// ---------------- kernel 0c: x transpose -> xT[b][hw][c] (f32) + xTb (bf16) ----
__global__ __launch_bounds__(256) void k_xtrans(const float* __restrict__ x,
                                                float* __restrict__ xT,
                                                unsigned short* __restrict__ xTb)
{
    __shared__ float tile[32][33];
    int bid = blockIdx.x;                 // b*(200*8) + hwt*8 + ct
    int ct  = bid & 7;
    int hwt = (bid >> 3) % 200;
    int b   = bid / 1600;
    int c0  = ct * 32, hw0 = hwt * 32;
    int tid = threadIdx.x;
    int col = tid & 31, rw = tid >> 5;    // 8 rows per pass
    const float* xb = x + (size_t)b * C1 * HWn;
    #pragma unroll
    for (int k = 0; k < 4; ++k) {
        int r = rw + k * 8;               // c-index
        tile[r][col] = xb[(size_t)(c0 + r) * HWn + hw0 + col];
    }
    __syncthreads();
    float* xo = xT + ((size_t)b * HWn + hw0) * C1 + c0;
    unsigned short* xob = xTb + ((size_t)b * HWn + hw0) * C1 + c0;
    #pragma unroll
    for (int k = 0; k < 4; ++k) {
        int r = rw + k * 8;               // hw-index
        float v = tile[col][r];
        xo[(size_t)r * C1 + col]  = v;
        xob[(size_t)r * C1 + col] = (unsigned short)f2bf(v);
    }
}

// ---------------- kernel 1b: offset conv v4 — MFMA, no LDS, no barriers --------
__global__ __launch_bounds__(256) void k_offmfma(const unsigned short* __restrict__ xTb,
                                                 const unsigned short* __restrict__ wOB,
                                                 const float* __restrict__ b_off,
                                                 float* __restrict__ off)
{
    int t  = threadIdx.x;
    int wv = t >> 6, lane = t & 63;
    int li = lane & 15, kg = lane >> 4;
    int mi = wv & 1;                   // m-tile (16 px)
    int nj = wv >> 1;                  // n-tile (16 oc)

    int mtile = ((blockIdx.x & 7) * 100) + (blockIdx.x >> 3);
    int m0  = mtile * 32;
    int b   = m0 / HWn;                // uniform per block
    int hw0 = m0 - b * HWn;
    int pxl = hw0 + mi * 16 + li;      // this lane's hw (A row)
    int h = pxl / Wc, w = pxl - h * Wc;

    const unsigned short* xb = xTb + (size_t)b * HWn * C1;

    f32x4 acc = (f32x4){0.f, 0.f, 0.f, 0.f};
    #pragma unroll
    for (int p = 0; p < 9; ++p) {
        int dh = p / 3 - 1, dw = p % 3 - 1;
        int hh = h + dh, ww = w + dw;
        bool valid = (hh >= 0 && hh < Hc && ww >= 0 && ww < Wc);
        int hwp = valid ? (hh * Wc + ww) : 0;
        const unsigned short* arow = xb + (size_t)hwp * C1 + kg * 8;
        const unsigned short* brow = wOB + ((size_t)(p * 8) * 32 + nj * 16 + li) * 32 + kg * 8;
        #pragma unroll
        for (int cc = 0; cc < 8; ++cc) {
            uint4 av = *(const uint4*)(arow + cc * 32);
            if (!valid) av = make_uint4(0, 0, 0, 0);
            uint4 bv = *(const uint4*)(brow + cc * 1024);   // next s: +32*32 u16
            acc = __builtin_amdgcn_mfma_f32_16x16x32_bf16(
                __builtin_bit_cast(bf16x8, av), __builtin_bit_cast(bf16x8, bv), acc, 0, 0, 0);
        }
    }
    int oc = nj * 16 + li;
    if (oc < OFFC) {
        float bs = b_off[oc];
        float4 v;
        v.x = acc[0] + bs; v.y = acc[1] + bs; v.z = acc[2] + bs; v.w = acc[3] + bs;
        int hwd = hw0 + mi * 16 + kg * 4;
        *(float4*)&off[((size_t)b * OFFC + oc) * HWn + hwd] = v;
    }
}

// ---------------- kernel 1c-pre: bilinear metadata table ----------------
__global__ __launch_bounds__(256) void k_meta(const float* __restrict__ off,
                                              int* __restrict__ crdbuf,
                                              float4* __restrict__ w4buf)
{
    int pair = blockIdx.x * 256 + threadIdx.x;   // 0 .. 230399
    int px = pair / 9, p = pair - px * 9;
    int b  = px / HWn, hw = px - b * HWn;
    int h = hw / Wc, w = hw - h * Wc;
    int ii = p / 3, jj = p - ii * 3;

    const float* ob = off + (size_t)b * OFFC * HWn + hw;
    float dy = ob[(2 * p) * HWn];
    float dx = ob[(2 * p + 1) * HWn];
    float mv = ob[(18 + p) * HWn];
    float mask = 1.0f / (1.0f + expf(-mv));
    float ys = dy + (float)(h - 1 + ii);
    float xsv = dx + (float)(w - 1 + jj);
    float y0f = floorf(ys), x0f = floorf(xsv);
    float wy = ys - y0f, wx = xsv - x0f;
    int y0 = (int)y0f, x0 = (int)x0f;
    int y1 = y0 + 1, x1 = x0 + 1;
    float vy0 = (y0 >= 0 && y0 < Hc) ? 1.f : 0.f;
    float vy1 = (y1 >= 0 && y1 < Hc) ? 1.f : 0.f;
    float vx0 = (x0 >= 0 && x0 < Wc) ? 1.f : 0.f;
    float vx1 = (x1 >= 0 && x1 < Wc) ? 1.f : 0.f;
    float4 wv;
    wv.x = mask * (1.f - wy) * (1.f - wx) * vy0 * vx0;
    wv.y = mask * (1.f - wy) * wx         * vy0 * vx1;
    wv.z = mask * wy         * (1.f - wx) * vy1 * vx0;
    wv.w = mask * wy         * wx         * vy1 * vx1;
    int cy0 = min(max(y0, 0), Hc - 1), cy1 = min(max(y1, 0), Hc - 1);
    int cx0 = min(max(x0, 0), Wc - 1), cx1 = min(max(x1, 0), Wc - 1);
    crdbuf[pair] = cy0 | (cy1 << 8) | (cx0 << 16) | (cx1 << 24);
    w4buf[pair]  = wv;
}

// ------------- kernel 2: FUSED deformable gather + MFMA GEMM v11b -------------
// round-21 NaN post-mortem: all index math re-derived and matches the three
// validated pieces (k_gather bilinear, r19/20 k-major global-B, r13 epilogue).
// Suspect: full 72-step unroll + launch_bounds(256,4) 128-VGPR cap -> heavy
// spill interacting with cvt_pk inline asm (rule #18/#20 family). This
// version: p-loop ROLLED (#pragma unroll 1), no min-wave bound. Logic
// byte-identical otherwise.
__global__ __launch_bounds__(256) void k_dfused(const float* __restrict__ xT,
                                                const int* __restrict__ crdbuf,
                                                const float4* __restrict__ w4buf,
                                                const unsigned short* __restrict__ wB1,
                                                const float* __restrict__ bias,
                                                float* __restrict__ out)
{
    __shared__ float Tb[32 * 33];      // epilogue transpose only

    int t  = threadIdx.x;
    int wv = t >> 6, lane = t & 63;
    int li = lane & 15, kg = lane >> 4;
    int mi = wv & 1;                   // m-tile (16 px)
    int nh = wv >> 1;                  // oc 128-half

    int mtile = ((blockIdx.x & 7) * 100) + (blockIdx.x >> 3);
    int m0  = mtile * 32;
    int b   = m0 / HWn;
    int hw0 = m0 - b * HWn;
    int px  = m0 + mi * 16 + li;       // this lane's global pixel row

    const float* xtb = xT + (size_t)b * HWn * C1;

    f32x4 acc[8];
    #pragma unroll
    for (int n = 0; n < 8; ++n) acc[n] = (f32x4){0.f, 0.f, 0.f, 0.f};

    #pragma unroll 1
    for (int p = 0; p < 9; ++p) {
        int pair = px * 9 + p;
        int crd = crdbuf[pair];
        float4 w4 = w4buf[pair];
        int cy0 = crd & 255, cy1 = (crd >> 8) & 255;
        int cx0 = (crd >> 16) & 255, cx1 = (crd >> 24) & 255;
        const float* c00 = &xtb[(size_t)(cy0 * Wc + cx0) * C1 + kg * 8];
        const float* c01 = &xtb[(size_t)(cy0 * Wc + cx1) * C1 + kg * 8];
        const float* c10 = &xtb[(size_t)(cy1 * Wc + cx0) * C1 + kg * 8];
        const float* c11 = &xtb[(size_t)(cy1 * Wc + cx1) * C1 + kg * 8];
        #pragma unroll
        for (int cc = 0; cc < 8; ++cc) {
            int s = p * 8 + cc;
            float4 a0 = *(const float4*)(c00 + cc * 32);
            float4 a1 = *(const float4*)(c00 + cc * 32 + 4);
            float4 b0 = *(const float4*)(c01 + cc * 32);
            float4 b1 = *(const float4*)(c01 + cc * 32 + 4);
            float4 d0 = *(const float4*)(c10 + cc * 32);
            float4 d1 = *(const float4*)(c10 + cc * 32 + 4);
            float4 e0 = *(const float4*)(c11 + cc * 32);
            float4 e1 = *(const float4*)(c11 + cc * 32 + 4);
            float v[8];
            v[0] = fmaf(w4.x, a0.x, fmaf(w4.y, b0.x, fmaf(w4.z, d0.x, w4.w * e0.x)));
            v[1] = fmaf(w4.x, a0.y, fmaf(w4.y, b0.y, fmaf(w4.z, d0.y, w4.w * e0.y)));
            v[2] = fmaf(w4.x, a0.z, fmaf(w4.y, b0.z, fmaf(w4.z, d0.z, w4.w * e0.z)));
            v[3] = fmaf(w4.x, a0.w, fmaf(w4.y, b0.w, fmaf(w4.z, d0.w, w4.w * e0.w)));
            v[4] = fmaf(w4.x, a1.x, fmaf(w4.y, b1.x, fmaf(w4.z, d1.x, w4.w * e1.x)));
            v[5] = fmaf(w4.x, a1.y, fmaf(w4.y, b1.y, fmaf(w4.z, d1.y, w4.w * e1.y)));
            v[6] = fmaf(w4.x, a1.z, fmaf(w4.y, b1.z, fmaf(w4.z, d1.z, w4.w * e1.z)));
            v[7] = fmaf(w4.x, a1.w, fmaf(w4.y, b1.w, fmaf(w4.z, d1.w, w4.w * e1.w)));
            unsigned h0 = packhi2(v[0], v[1]);
            unsigned h1 = packhi2(v[2], v[3]);
            unsigned h2 = packhi2(v[4], v[5]);
            unsigned h3 = packhi2(v[6], v[7]);
            bf16x8 av = __builtin_bit_cast(bf16x8, make_uint4(h0, h1, h2, h3));
            // wB1[s][kg][oc][8]: oc = nh*128 + nt*16 + li
            const unsigned short* bq = wB1 + ((size_t)(s * 4 + kg) * 256 + nh * 128 + li) * 8;
            #pragma unroll
            for (int nt = 0; nt < 8; ++nt) {
                bf16x8 bv = *(const bf16x8*)(bq + nt * 128);
                acc[nt] = __builtin_amdgcn_mfma_f32_16x16x32_bf16(av, bv, acc[nt], 0, 0, 0);
            }
        }
    }

    // ---- epilogue: 8 phases of 32 oc through Tb[32][33] (r13-verified) ----
    // D frag: pixel = mi*16 + kg*4 + r ; oc = nh*128 + nt*16 + li
    #pragma unroll
    for (int q = 0; q < 8; ++q) {
        __syncthreads();
        if (nh == (q >> 2)) {
            #pragma unroll
            for (int j = 0; j < 2; ++j) {
                int nt = (q & 3) * 2 + j;
                f32x4 a = acc[nt];
                int row = j * 16 + li;              // oc row 0..31
                int col = mi * 16 + kg * 4;         // pixel col
                #pragma unroll
                for (int r = 0; r < 4; ++r)
                    Tb[row * 33 + col + r] = a[r];
            }
        }
        __syncthreads();
        int pxs = t & 31;
        int rw = t >> 5;                    // 0..7
        #pragma unroll
        for (int it = 0; it < 4; ++it) {
            int r  = it * 8 + rw;           // 0..31
            int oc = q * 32 + r;
            out[(size_t)(b * C2 + oc) * HWn + hw0 + pxs] = Tb[r * 33 + pxs] + bias[oc];
        }
    }
}

// ---------------- kernel 3: BN stats (per-channel mean, invstd) ----------------
__global__ __launch_bounds__(256) void k_bnstats(const float* __restrict__ out,
                                                 float* __restrict__ stats)
{
    int oc = blockIdx.x;
    double s = 0.0, ss = 0.0;
    for (int i = threadIdx.x; i < NPIX; i += 256) {
        int bb = i / HWn;
        int hw = i - bb * HWn;
        float v = out[(size_t)(bb * C2 + oc) * HWn + hw];
        s  += (double)v;
        ss += (double)v * (double)v;
    }
    __shared__ double ls[256], lss[256];
    ls[threadIdx.x] = s; lss[threadIdx.x] = ss;
    __syncthreads();
    for (int st = 128; st > 0; st >>= 1) {
        if (threadIdx.x < st) {
            ls[threadIdx.x]  += ls[threadIdx.x + st];
            lss[threadIdx.x] += lss[threadIdx.x + st];
        }
        __syncthreads();
    }
    if (threadIdx.x == 0) {
        double mean = ls[0] / (double)NPIX;
        double var  = lss[0] / (double)NPIX - mean * mean;
        stats[oc]       = (float)mean;
        stats[256 + oc] = (float)(1.0 / sqrt(var + 1e-5));
    }
}

// ---------------- kernel 4: BN normalize + affine + SiLU (in-place) ----------------
__global__ __launch_bounds__(256) void k_bnsilu(float* __restrict__ out,
                                                const float* __restrict__ stats,
                                                const float* __restrict__ gamma,
                                                const float* __restrict__ beta)
{
    int n4 = (Bn * C2 * HWn) / 4;
    for (int i = blockIdx.x * blockDim.x + threadIdx.x; i < n4;
         i += gridDim.x * blockDim.x) {
        float4 v = ((float4*)out)[i];
        int e  = i * 4;
        int oc = (e / HWn) & 255;
        float mean = stats[oc];
        float gs   = gamma[oc] * stats[256 + oc];
        float bt   = beta[oc];
        float y;
        y = (v.x - mean) * gs + bt; v.x = y / (1.f + expf(-y));
        y = (v.y - mean) * gs + bt; v.y = y / (1.f + expf(-y));
        y = (v.z - mean) * gs + bt; v.z = y / (1.f + expf(-y));
        y = (v.w - mean) * gs + bt; v.w = y / (1.f + expf(-y));
        ((float4*)out)[i] = v;
    }
}

extern "C" void kernel_launch(void* const* d_in, const int* in_sizes, int n_in,
                              void* d_out, int out_size, void* d_ws, size_t ws_size,
                              hipStream_t stream)
{
    const float* x      = (const float*)d_in[0];
    const float* w_off  = (const float*)d_in[1];
    const float* b_off  = (const float*)d_in[2];
    const float* weight = (const float*)d_in[3];
    const float* bias   = (const float*)d_in[4];
    const float* gamma  = (const float*)d_in[5];
    const float* beta   = (const float*)d_in[6];
    float* out = (float*)d_out;

    // workspace layout (~47 MiB total)
    char* wsb = (char*)d_ws;
    float*          xT   = (float*)(wsb);                          //  26,214,400 B
    unsigned short* xTb  = (unsigned short*)(wsb + 26214400);      //  13,107,200 B
    float*          off  = (float*)(wsb + 39321600);               //   2,764,800 B
    unsigned short* wB1  = (unsigned short*)(wsb + 42086400);      //   1,179,648 B
    unsigned short* wOB  = (unsigned short*)(wsb + 43266048);      //     147,456 B
    int*            crdb = (int*)(wsb + 43413504);                 //     921,600 B
    float4*         w4b  = (float4*)(wsb + 44335104);              //   3,686,400 B
    float*         stats = (float*)(wsb + 48021504);               //       2,048 B

    k_wprep    <<<2304, 256, 0, stream>>>(weight, wB1);
    k_wobprep  <<<288, 256, 0, stream>>>(w_off, wOB);
    k_xtrans   <<<6400, 256, 0, stream>>>(x, xT, xTb);
    k_offmfma  <<<800, 256, 0, stream>>>(xTb, wOB, b_off, off);
    k_meta     <<<900, 256, 0, stream>>>(off, crdb, w4b);
    k_dfused   <<<800, 256, 0, stream>>>(xT, crdb, w4b, wB1, bias, out);
    k_bnstats  <<<256, 256, 0, stream>>>(out, stats);
    k_bnsilu   <<<2048, 256, 0, stream>>>(out, stats, gamma, beta);
}

// Round 23
// 249.766 us; speedup vs baseline: 1.7872x; 1.7872x over previous
//
#include <hip/hip_runtime.h>
#include <math.h>

constexpr int Hc = 80, Wc = 80, Bn = 4, C1 = 256, C2 = 256;
constexpr int HWn = Hc * Wc;          // 6400
constexpr int NPIX = Bn * HWn;        // 25600
constexpr int OFFC = 27;
constexpr int KK   = 2304;            // C1*9

typedef short bf16x8 __attribute__((ext_vector_type(8)));
typedef float f32x4  __attribute__((ext_vector_type(4)));

__device__ __forceinline__ unsigned f2bf(float f) {   // RNE to bf16 bits
    unsigned u = __float_as_uint(f);
    return (u + 0x7FFF + ((u >> 16) & 1)) >> 16;
}

// pack 2 floats -> 1 u32 of 2 bf16 via cvt_pk (RNE)
__device__ __forceinline__ unsigned packhi2(float v0, float v1) {
    unsigned h;
    asm("v_cvt_pk_bf16_f32 %0, %1, %2" : "=v"(h) : "v"(v0), "v"(v1));
    return h;
}

// ---------------- kernel 0a: weight prep -> per-step B images, K-MAJOR ----------
// wB1[s][kg][oc][8] bf16, s = p*8+cc (72 steps), kg = k-quad (8 k each).
__global__ __launch_bounds__(256) void k_wprep(const float* __restrict__ weight,
                                               unsigned short* __restrict__ wB1)
{
    int e = blockIdx.x * 256 + threadIdx.x;   // 0 .. 589823
    int kin = e & 7;
    int oc  = (e >> 3) & 255;
    int kg  = (e >> 11) & 3;
    int s   = e >> 13;                        // 0..71
    int p   = s >> 3, cc = s & 7;
    float w = weight[((size_t)oc * C1 + cc * 32 + kg * 8 + kin) * 9 + p];
    wB1[e] = (unsigned short)f2bf(w);
}

// ---------------- kernel 0b: offset-conv MFMA weight prep -> wOB[s][32][32] ----
__global__ __launch_bounds__(256) void k_wobprep(const float* __restrict__ w_off,
                                                 unsigned short* __restrict__ wOB)
{
    int e = blockIdx.x * 256 + threadIdx.x;   // 0 .. 73727
    int k  = e & 31;
    int oc = (e >> 5) & 31;
    int s  = e >> 10;                         // 0..71
    int p  = s >> 3, cc = s & 7;
    float v = 0.f;
    if (oc < 27) v = w_off[((size_t)oc * C1 + cc * 32 + k) * 9 + p];
    wOB[e] = (unsigned short)f2bf(v);
}

// ---------------- kernel 0c: x transpose -> xT[b][hw][c] (f32) + xTb (bf16) ----
__global__ __launch_bounds__(256) void k_xtrans(const float* __restrict__ x,
                                                float* __restrict__ xT,
                                                unsigned short* __restrict__ xTb)
{
    __shared__ float tile[32][33];
    int bid = blockIdx.x;                 // b*(200*8) + hwt*8 + ct
    int ct  = bid & 7;
    int hwt = (bid >> 3) % 200;
    int b   = bid / 1600;
    int c0  = ct * 32, hw0 = hwt * 32;
    int tid = threadIdx.x;
    int col = tid & 31, rw = tid >> 5;    // 8 rows per pass
    const float* xb = x + (size_t)b * C1 * HWn;
    #pragma unroll
    for (int k = 0; k < 4; ++k) {
        int r = rw + k * 8;               // c-index
        tile[r][col] = xb[(size_t)(c0 + r) * HWn + hw0 + col];
    }
    __syncthreads();
    float* xo = xT + ((size_t)b * HWn + hw0) * C1 + c0;
    unsigned short* xob = xTb + ((size_t)b * HWn + hw0) * C1 + c0;
    #pragma unroll
    for (int k = 0; k < 4; ++k) {
        int r = rw + k * 8;               // hw-index
        float v = tile[col][r];
        xo[(size_t)r * C1 + col]  = v;
        xob[(size_t)r * C1 + col] = (unsigned short)f2bf(v);
    }
}

// ---------------- kernel 1b: offset conv v4 — MFMA, no LDS, no barriers --------
__global__ __launch_bounds__(256) void k_offmfma(const unsigned short* __restrict__ xTb,
                                                 const unsigned short* __restrict__ wOB,
                                                 const float* __restrict__ b_off,
                                                 float* __restrict__ off)
{
    int t  = threadIdx.x;
    int wv = t >> 6, lane = t & 63;
    int li = lane & 15, kg = lane >> 4;
    int mi = wv & 1;                   // m-tile (16 px)
    int nj = wv >> 1;                  // n-tile (16 oc)

    int mtile = ((blockIdx.x & 7) * 100) + (blockIdx.x >> 3);
    int m0  = mtile * 32;
    int b   = m0 / HWn;                // uniform per block
    int hw0 = m0 - b * HWn;
    int pxl = hw0 + mi * 16 + li;      // this lane's hw (A row)
    int h = pxl / Wc, w = pxl - h * Wc;

    const unsigned short* xb = xTb + (size_t)b * HWn * C1;

    f32x4 acc = (f32x4){0.f, 0.f, 0.f, 0.f};
    #pragma unroll
    for (int p = 0; p < 9; ++p) {
        int dh = p / 3 - 1, dw = p % 3 - 1;
        int hh = h + dh, ww = w + dw;
        bool valid = (hh >= 0 && hh < Hc && ww >= 0 && ww < Wc);
        int hwp = valid ? (hh * Wc + ww) : 0;
        const unsigned short* arow = xb + (size_t)hwp * C1 + kg * 8;
        const unsigned short* brow = wOB + ((size_t)(p * 8) * 32 + nj * 16 + li) * 32 + kg * 8;
        #pragma unroll
        for (int cc = 0; cc < 8; ++cc) {
            uint4 av = *(const uint4*)(arow + cc * 32);
            if (!valid) av = make_uint4(0, 0, 0, 0);
            uint4 bv = *(const uint4*)(brow + cc * 1024);   // next s: +32*32 u16
            acc = __builtin_amdgcn_mfma_f32_16x16x32_bf16(
                __builtin_bit_cast(bf16x8, av), __builtin_bit_cast(bf16x8, bv), acc, 0, 0, 0);
        }
    }
    int oc = nj * 16 + li;
    if (oc < OFFC) {
        float bs = b_off[oc];
        float4 v;
        v.x = acc[0] + bs; v.y = acc[1] + bs; v.z = acc[2] + bs; v.w = acc[3] + bs;
        int hwd = hw0 + mi * 16 + kg * 4;
        *(float4*)&off[((size_t)b * OFFC + oc) * HWn + hwd] = v;
    }
}

// ---------------- kernel 1c-pre: bilinear metadata table ----------------
__global__ __launch_bounds__(256) void k_meta(const float* __restrict__ off,
                                              int* __restrict__ crdbuf,
                                              float4* __restrict__ w4buf)
{
    int pair = blockIdx.x * 256 + threadIdx.x;   // 0 .. 230399
    int px = pair / 9, p = pair - px * 9;
    int b  = px / HWn, hw = px - b * HWn;
    int h = hw / Wc, w = hw - h * Wc;
    int ii = p / 3, jj = p - ii * 3;

    const float* ob = off + (size_t)b * OFFC * HWn + hw;
    float dy = ob[(2 * p) * HWn];
    float dx = ob[(2 * p + 1) * HWn];
    float mv = ob[(18 + p) * HWn];
    float mask = 1.0f / (1.0f + expf(-mv));
    float ys = dy + (float)(h - 1 + ii);
    float xsv = dx + (float)(w - 1 + jj);
    float y0f = floorf(ys), x0f = floorf(xsv);
    float wy = ys - y0f, wx = xsv - x0f;
    int y0 = (int)y0f, x0 = (int)x0f;
    int y1 = y0 + 1, x1 = x0 + 1;
    float vy0 = (y0 >= 0 && y0 < Hc) ? 1.f : 0.f;
    float vy1 = (y1 >= 0 && y1 < Hc) ? 1.f : 0.f;
    float vx0 = (x0 >= 0 && x0 < Wc) ? 1.f : 0.f;
    float vx1 = (x1 >= 0 && x1 < Wc) ? 1.f : 0.f;
    float4 wv;
    wv.x = mask * (1.f - wy) * (1.f - wx) * vy0 * vx0;
    wv.y = mask * (1.f - wy) * wx         * vy0 * vx1;
    wv.z = mask * wy         * (1.f - wx) * vy1 * vx0;
    wv.w = mask * wy         * wx         * vy1 * vx1;
    int cy0 = min(max(y0, 0), Hc - 1), cy1 = min(max(y1, 0), Hc - 1);
    int cx0 = min(max(x0, 0), Wc - 1), cx1 = min(max(x1, 0), Wc - 1);
    crdbuf[pair] = cy0 | (cy1 << 8) | (cx0 << 16) | (cx1 << 24);
    w4buf[pair]  = wv;
}

// ---------------- kernel 1c: materialize patches v5 (channel-dense reads) -------
__global__ __launch_bounds__(256) void k_gather(const float* __restrict__ xT,
                                                const int* __restrict__ crdbuf,
                                                const float4* __restrict__ w4buf,
                                                unsigned short* __restrict__ Ahi)
{
    int t   = threadIdx.x;
    int wv  = t >> 6, l = t & 63;
    int xcd = blockIdx.x & 7;
    int blk = blockIdx.x >> 3;               // 0..99 within XCD
    int wgl = (xcd * 100 + blk) * 4 + wv;    // global wave 0..3199
    int base = wgl * 72;

    #pragma unroll 2
    for (int i = 0; i < 72; ++i) {
        int pair = base + i;
        int px = pair / 9, p = pair - px * 9;
        int b  = px / HWn;
        int crd = crdbuf[pair];
        float4 w4 = w4buf[pair];
        int cy0 = crd & 255, cy1 = (crd >> 8) & 255;
        int cx0 = (crd >> 16) & 255, cx1 = (crd >> 24) & 255;
        const float* xt = xT + (size_t)b * HWn * C1;
        const float4* g00p = (const float4*)&xt[(size_t)(cy0 * Wc + cx0) * C1];
        const float4* g01p = (const float4*)&xt[(size_t)(cy0 * Wc + cx1) * C1];
        const float4* g10p = (const float4*)&xt[(size_t)(cy1 * Wc + cx0) * C1];
        const float4* g11p = (const float4*)&xt[(size_t)(cy1 * Wc + cx1) * C1];
        float4 g00 = g00p[l], g01 = g01p[l], g10 = g10p[l], g11 = g11p[l];
        float vx = fmaf(w4.x, g00.x, fmaf(w4.y, g01.x, fmaf(w4.z, g10.x, w4.w * g11.x)));
        float vy = fmaf(w4.x, g00.y, fmaf(w4.y, g01.y, fmaf(w4.z, g10.y, w4.w * g11.y)));
        float vz = fmaf(w4.x, g00.z, fmaf(w4.y, g01.z, fmaf(w4.z, g10.z, w4.w * g11.z)));
        float vw = fmaf(w4.x, g00.w, fmaf(w4.y, g01.w, fmaf(w4.z, g10.w, w4.w * g11.w)));
        unsigned h0 = packhi2(vx, vy), h1 = packhi2(vz, vw);
        int s = p * 8 + (l >> 3);
        size_t aidx = ((size_t)s * NPIX + px) * 32 + 4 * (l & 7);
        *(uint2*)&Ahi[aidx] = make_uint2(h0, h1);
    }
}

// ------------- kernel 2: dense streaming MFMA GEMM v12 — deep A-prefetch -------------
// round-22: reverted the fused experiment (345us — corner loads back on the
// wave critical path; split wins). r20's barrier-free v10 was latency-bound:
// 2-stage pipeline covers ~40cyc of the ~500cyc A-load (L3) latency at only
// ~12 waves/CU. v12: MIXED-DEPTH register prefetch — A issued 4 steps ahead
// (A0..A3 rotation), B (L2-resident, ~200cyc) 2 ahead (B0/B1). Staging =
// 64 VGPR; compiler-tracked counted waits per register. 72 = 4x18 steps.
__global__ __launch_bounds__(256) void k_dmfma(const unsigned short* __restrict__ Ahi,
                                               const unsigned short* __restrict__ wB1,
                                               const float* __restrict__ bias,
                                               float* __restrict__ out)
{
    __shared__ float Tb[32 * 33];      // epilogue transpose only (4224 B)

    int t  = threadIdx.x;
    int wv = t >> 6, lane = t & 63;
    int li = lane & 15, kg = lane >> 4;
    int nh = wv;                       // oc 64-slot (4 waves x 64 oc)

    int mtile = ((blockIdx.x & 7) * 100) + (blockIdx.x >> 3);
    int m0  = mtile * 32;
    int b   = m0 / HWn;
    int hw0 = m0 - b * HWn;
    int row0 = m0 + li;                // m-frag 0 row
    int row1 = m0 + 16 + li;           // m-frag 1 row

    const unsigned short* a0p = Ahi + (size_t)row0 * 32 + kg * 8;
    const unsigned short* a1p = Ahi + (size_t)row1 * 32 + kg * 8;
    const unsigned short* bp  = wB1 + (size_t)(kg * 256 + nh * 64 + li) * 8;

    auto loadA = [&](int s, uint4& h0, uint4& h1) {
        size_t o = (size_t)s * NPIX * 32;
        h0 = *(const uint4*)(a0p + o);
        h1 = *(const uint4*)(a1p + o);
    };
    auto loadB = [&](int s, uint4& b0, uint4& b1, uint4& b2, uint4& b3) {
        const unsigned short* q = bp + (size_t)s * 8192;
        b0 = *(const uint4*)(q);
        b1 = *(const uint4*)(q + 128);     // nt*16*8 u16
        b2 = *(const uint4*)(q + 256);
        b3 = *(const uint4*)(q + 384);
    };

    f32x4 acc[2][4];
    #pragma unroll
    for (int m = 0; m < 2; ++m)
        #pragma unroll
        for (int n = 0; n < 4; ++n) acc[m][n] = (f32x4){0.f, 0.f, 0.f, 0.f};

    // A prefetch slots (4-deep), B slots (2-deep) — static names (rule #20)
    uint4 A0a, A0b, A1a, A1b, A2a, A2b, A3a, A3b;
    uint4 B0q0, B0q1, B0q2, B0q3, B1q0, B1q1, B1q2, B1q3;

    auto compute = [&](uint4& c0, uint4& c1, uint4& q0, uint4& q1, uint4& q2, uint4& q3) {
        bf16x8 a0 = __builtin_bit_cast(bf16x8, c0);
        bf16x8 a1 = __builtin_bit_cast(bf16x8, c1);
        __builtin_amdgcn_s_setprio(1);
        bf16x8 v;
        v = __builtin_bit_cast(bf16x8, q0);
        acc[0][0] = __builtin_amdgcn_mfma_f32_16x16x32_bf16(a0, v, acc[0][0], 0, 0, 0);
        acc[1][0] = __builtin_amdgcn_mfma_f32_16x16x32_bf16(a1, v, acc[1][0], 0, 0, 0);
        v = __builtin_bit_cast(bf16x8, q1);
        acc[0][1] = __builtin_amdgcn_mfma_f32_16x16x32_bf16(a0, v, acc[0][1], 0, 0, 0);
        acc[1][1] = __builtin_amdgcn_mfma_f32_16x16x32_bf16(a1, v, acc[1][1], 0, 0, 0);
        v = __builtin_bit_cast(bf16x8, q2);
        acc[0][2] = __builtin_amdgcn_mfma_f32_16x16x32_bf16(a0, v, acc[0][2], 0, 0, 0);
        acc[1][2] = __builtin_amdgcn_mfma_f32_16x16x32_bf16(a1, v, acc[1][2], 0, 0, 0);
        v = __builtin_bit_cast(bf16x8, q3);
        acc[0][3] = __builtin_amdgcn_mfma_f32_16x16x32_bf16(a0, v, acc[0][3], 0, 0, 0);
        acc[1][3] = __builtin_amdgcn_mfma_f32_16x16x32_bf16(a1, v, acc[1][3], 0, 0, 0);
        __builtin_amdgcn_s_setprio(0);
    };

    // prologue: A 4-deep, B 2-deep
    loadA(0, A0a, A0b); loadA(1, A1a, A1b); loadA(2, A2a, A2b); loadA(3, A3a, A3b);
    loadB(0, B0q0, B0q1, B0q2, B0q3); loadB(1, B1q0, B1q1, B1q2, B1q3);

    for (int s = 0; s < 72; s += 4) {
        compute(A0a, A0b, B0q0, B0q1, B0q2, B0q3);
        if (s + 4 < 72) loadA(s + 4, A0a, A0b);
        loadB(s + 2, B0q0, B0q1, B0q2, B0q3);
        compute(A1a, A1b, B1q0, B1q1, B1q2, B1q3);
        if (s + 5 < 72) loadA(s + 5, A1a, A1b);
        loadB(s + 3, B1q0, B1q1, B1q2, B1q3);
        compute(A2a, A2b, B0q0, B0q1, B0q2, B0q3);
        if (s + 6 < 72) loadA(s + 6, A2a, A2b);
        if (s + 4 < 72) loadB(s + 4, B0q0, B0q1, B0q2, B0q3);
        compute(A3a, A3b, B1q0, B1q1, B1q2, B1q3);
        if (s + 7 < 72) loadA(s + 7, A3a, A3b);
        if (s + 5 < 72) loadB(s + 5, B1q0, B1q1, B1q2, B1q3);
    }

    // ---- epilogue: 8 phases of 32 oc through Tb[32][33] ----
    // D frag: px = m*16 + kg*4 + r ; oc = nh*64 + nt*16 + li.
    // Phase q: oc in [q*32, q*32+32) -> nh == q>>1, nt = (q&1)*2 + jj.
    #pragma unroll
    for (int q = 0; q < 8; ++q) {
        __syncthreads();
        if (nh == (q >> 1)) {
            #pragma unroll
            for (int jj = 0; jj < 2; ++jj) {
                int nt = (q & 1) * 2 + jj;
                #pragma unroll
                for (int m = 0; m < 2; ++m) {
                    f32x4 a = acc[m][nt];
                    int rrw = jj * 16 + li;             // oc row 0..31
                    int col = m * 16 + kg * 4;          // pixel col
                    #pragma unroll
                    for (int r = 0; r < 4; ++r)
                        Tb[rrw * 33 + col + r] = a[r];
                }
            }
        }
        __syncthreads();
        int px = t & 31;
        int rw = t >> 5;                    // 0..7
        #pragma unroll
        for (int it = 0; it < 4; ++it) {
            int r  = it * 8 + rw;           // 0..31
            int oc = q * 32 + r;
            out[(size_t)(b * C2 + oc) * HWn + hw0 + px] = Tb[r * 33 + px] + bias[oc];
        }
    }
}

// ---------------- kernel 3: BN stats (per-channel mean, invstd) ----------------
__global__ __launch_bounds__(256) void k_bnstats(const float* __restrict__ out,
                                                 float* __restrict__ stats)
{
    int oc = blockIdx.x;
    double s = 0.0, ss = 0.0;
    for (int i = threadIdx.x; i < NPIX; i += 256) {
        int bb = i / HWn;
        int hw = i - bb * HWn;
        float v = out[(size_t)(bb * C2 + oc) * HWn + hw];
        s  += (double)v;
        ss += (double)v * (double)v;
    }
    __shared__ double ls[256], lss[256];
    ls[threadIdx.x] = s; lss[threadIdx.x] = ss;
    __syncthreads();
    for (int st = 128; st > 0; st >>= 1) {
        if (threadIdx.x < st) {
            ls[threadIdx.x]  += ls[threadIdx.x + st];
            lss[threadIdx.x] += lss[threadIdx.x + st];
        }
        __syncthreads();
    }
    if (threadIdx.x == 0) {
        double mean = ls[0] / (double)NPIX;
        double var  = lss[0] / (double)NPIX - mean * mean;
        stats[oc]       = (float)mean;
        stats[256 + oc] = (float)(1.0 / sqrt(var + 1e-5));
    }
}

// ---------------- kernel 4: BN normalize + affine + SiLU (in-place) ----------------
__global__ __launch_bounds__(256) void k_bnsilu(float* __restrict__ out,
                                                const float* __restrict__ stats,
                                                const float* __restrict__ gamma,
                                                const float* __restrict__ beta)
{
    int n4 = (Bn * C2 * HWn) / 4;
    for (int i = blockIdx.x * blockDim.x + threadIdx.x; i < n4;
         i += gridDim.x * blockDim.x) {
        float4 v = ((float4*)out)[i];
        int e  = i * 4;
        int oc = (e / HWn) & 255;
        float mean = stats[oc];
        float gs   = gamma[oc] * stats[256 + oc];
        float bt   = beta[oc];
        float y;
        y = (v.x - mean) * gs + bt; v.x = y / (1.f + expf(-y));
        y = (v.y - mean) * gs + bt; v.y = y / (1.f + expf(-y));
        y = (v.z - mean) * gs + bt; v.z = y / (1.f + expf(-y));
        y = (v.w - mean) * gs + bt; v.w = y / (1.f + expf(-y));
        ((float4*)out)[i] = v;
    }
}

extern "C" void kernel_launch(void* const* d_in, const int* in_sizes, int n_in,
                              void* d_out, int out_size, void* d_ws, size_t ws_size,
                              hipStream_t stream)
{
    const float* x      = (const float*)d_in[0];
    const float* w_off  = (const float*)d_in[1];
    const float* b_off  = (const float*)d_in[2];
    const float* weight = (const float*)d_in[3];
    const float* bias   = (const float*)d_in[4];
    const float* gamma  = (const float*)d_in[5];
    const float* beta   = (const float*)d_in[6];
    float* out = (float*)d_out;

    // workspace layout (~158 MiB total)
    char* wsb = (char*)d_ws;
    unsigned short* Ahi  = (unsigned short*)(wsb);                 // 117,964,800 B
    float*          xT   = (float*)(wsb + 117964800);              //  26,214,400 B
    unsigned short* xTb  = (unsigned short*)(wsb + 144179200);     //  13,107,200 B
    float*          off  = (float*)(wsb + 157286400);              //   2,764,800 B
    unsigned short* wB1  = (unsigned short*)(wsb + 160051200);     //   1,179,648 B
    unsigned short* wOB  = (unsigned short*)(wsb + 161230848);     //     147,456 B
    int*            crdb = (int*)(wsb + 161378304);                //     921,600 B
    float4*         w4b  = (float4*)(wsb + 162299904);             //   3,686,400 B
    float*         stats = (float*)(wsb + 165986304);              //       2,048 B

    k_wprep    <<<2304, 256, 0, stream>>>(weight, wB1);
    k_wobprep  <<<288, 256, 0, stream>>>(w_off, wOB);
    k_xtrans   <<<6400, 256, 0, stream>>>(x, xT, xTb);
    k_offmfma  <<<800, 256, 0, stream>>>(xTb, wOB, b_off, off);
    k_meta     <<<900, 256, 0, stream>>>(off, crdb, w4b);
    k_gather   <<<800, 256, 0, stream>>>(xT, crdb, w4b, Ahi);
    k_dmfma    <<<800, 256, 0, stream>>>(Ahi, wB1, bias, out);
    k_bnstats  <<<256, 256, 0, stream>>>(out, stats);
    k_bnsilu   <<<2048, 256, 0, stream>>>(out, stats, gamma, beta);
}